// Round 11
// baseline (733.261 us; speedup 1.0000x reference)
//
#include <hip/hip_runtime.h>

#define SEQ 64

typedef _Float16 f16;
typedef _Float16 f16x8 __attribute__((ext_vector_type(8)));
typedef float f32x4 __attribute__((ext_vector_type(4)));

__device__ __forceinline__ float sig_(float x) { return 1.0f / (1.0f + __expf(-x)); }
__device__ __forceinline__ float tanh_(float x) { return 1.0f - 2.0f / (1.0f + __expf(2.0f * x)); }

template<int CTRL, int RMASK>
__device__ __forceinline__ float dpp_add(float x) {
  const int t = __builtin_amdgcn_update_dpp(0, __float_as_int(x), CTRL, RMASK, 0xF, true);
  return x + __int_as_float(t);
}
template<int CTRL>
__device__ __forceinline__ float dpp_max(float x) {
  const int t = __builtin_amdgcn_update_dpp(0, __float_as_int(x), CTRL, 0xF, 0xF, true);
  return fmaxf(x, __int_as_float(t));
}

// h state: node-major, 128 f16/row, XOR-swizzled in 8-f16 (16B) blocks
__device__ __forceinline__ int hOff(int n, int f) {
  return n * 128 + ((((f >> 3) ^ (n & 15)) << 3) | (f & 7));
}

// ---- prep: comp_W -> f16 B-fragment order; also out <- cbias broadcast ----
__global__ void prep_kernel(const float* __restrict__ cW, f16* __restrict__ wsB,
                            const float* __restrict__ cbias, float* __restrict__ out) {
  const int idx  = blockIdx.x * 256 + threadIdx.x;   // 0..20479
  if (blockIdx.x == 0 && threadIdx.x < 192)
    out[threadIdx.x] = cbias[threadIdx.x % 3];       // init logits with bias
  const int kk   = idx / 2560;
  const int rem  = idx - kk * 2560;
  const int nt   = rem >> 6;
  const int lane = rem & 63;
  const int col  = nt * 16 + (lane & 15);
  const int kb   = kk * 32 + ((lane >> 4) << 3);
  f16x8 v;
  #pragma unroll
  for (int j = 0; j < 8; ++j) v[j] = (f16)cW[(kb + j) * 640 + col];
  ((f16x8*)wsB)[idx] = v;
}

// Dynamic-LDS partition (148.5 KiB total; 1 block/CU, 160 KiB available)
#define BLDS_OFF 0              // 12 B-frag sets: 12*512*16 = 98304
#define CS_OFF   98304          // c state f32: 65*132*4 = 34320
#define HS_OFF   132624         // h state f16 swizzled: 65*128*2 = 16640
#define LGP_OFF  149264         // logit partials: 8*64*4 = 2048
#define PS_OFF   151312         // p: 64*4
#define CLS_OFF  151568         // copy_left: 64*4
#define CRS_OFF  151824         // copy_right: 64*4
#define DYN_LDS  152080

// ---- pyramid: 512 threads (8 waves, 2/SIMD). Unified budget 256/wave is
// split 128 arch + 128 accum by the compiler when MFMA is present (measured
// R3-R10: VGPR_Count pinned at 128 regardless of launch bounds). So we place
// exactly 26 B-sets (104 regs) in AGPRs (+20 acc = 124 <= 128) and keep the
// arch side at ~110. R6 pinned 40 sets (180 > 128) and overflowed — count
// is everything. ----
__global__ __launch_bounds__(512, 1) void pyramid_kernel(
    const int*   __restrict__ sentences,
    const float* __restrict__ emb,
    const f16*   __restrict__ wsB,
    const float* __restrict__ cb, const float* __restrict__ selw, const float* __restrict__ selb,
    float* __restrict__ finT)
{
  extern __shared__ __align__(16) char dyn[];
  f16x8* Blds = (f16x8*)(dyn + BLDS_OFF);
  float* cS   = (float*)(dyn + CS_OFF);
  f16*   hS   = (f16*)  (dyn + HS_OFF);
  float* lgp  = (float*)(dyn + LGP_OFF);
  float* pS   = (float*)(dyn + PS_OFF);
  float* clS  = (float*)(dyn + CLS_OFF);
  float* crS  = (float*)(dyn + CRS_OFF);

  const int tid  = threadIdx.x;
  const int b    = blockIdx.x;
  const int wv   = tid >> 6;
  const int lane = tid & 63;
  const int quad = lane >> 4;
  const int l15  = lane & 15;
  const int d    = wv * 16 + l15;
  const f16x8* Bf = (const f16x8*)wsB;

  // ---- persistent B in regs: q=0..2 all kk (24) + q=3,kk=0..3 (4) = 28 sets ----
  f16x8 Breg[28];
  #pragma unroll
  for (int kk = 0; kk < 8; ++kk)
    #pragma unroll
    for (int q = 0; q < 3; ++q)
      Breg[kk * 3 + q] = Bf[((kk * 40 + q * 8 + wv) << 6) + lane];
  #pragma unroll
  for (int kk = 0; kk < 4; ++kk)
    Breg[24 + kk] = Bf[((kk * 40 + 3 * 8 + wv) << 6) + lane];
  // pin 26 of 28 sets into the AGPR half (104 regs; +20 acc = 124 <= 128)
  #pragma unroll
  for (int i = 0; i < 26; ++i) asm volatile("" : "+a"(Breg[i]));

  // ---- B in LDS: s<4 -> (kk=4+s, q=3); s>=4 -> (kk=s-4, q=4) ----
  #pragma unroll
  for (int s = 0; s < 12; ++s) {
    const int kk = (s < 4) ? (4 + s) : (s - 4);
    const int q  = (s < 4) ? 3 : 4;
    Blds[s * 512 + tid] = Bf[((kk * 40 + q * 8 + wv) << 6) + lane];
  }

  // ---- embedding gather: h -> LDS f16, c -> LDS f32 ----
  {
    const int s = tid >> 3, part = tid & 7;
    const int row = sentences[b * SEQ + s];
    const float4* er = (const float4*)(emb + (size_t)row * 256 + part * 32);
    #pragma unroll
    for (int i4 = 0; i4 < 8; ++i4) {
      const float4 v = er[i4];
      const float vv[4] = {v.x, v.y, v.z, v.w};
      #pragma unroll
      for (int c = 0; c < 4; ++c) {
        const int f = part * 32 + i4 * 4 + c;
        if (f < 128) hS[hOff(s, f)] = (f16)vv[c];
        else         cS[s * 132 + (f - 128)] = vv[c];
      }
    }
  }
  if (tid < 128) hS[64 * 128 + tid] = (f16)0.f;   // guard row (node 64)
  if (tid < 132) cS[64 * 132 + tid] = 0.f;
  __syncthreads();

  float bq[5];
  #pragma unroll
  for (int q = 0; q < 5; ++q) bq[q] = cb[q * 128 + d];
  const float swh = selw[d], swc = selw[128 + d], selbv = selb[0];

  // ---- pyramid: 63 sequential layers; zero global memory in the loop ----
  for (int W = 63; W >= 1; --W) {
    const int NMT = (W + 15) >> 4;
    float chF[4][4], ccF[4][4];

    // ---- phase A: MFMA + gate epilogue, one mt at a time ----
    #pragma unroll
    for (int mt = 0; mt < 4; ++mt) if (mt < NMT) {
      f32x4 acc[5];
      #pragma unroll
      for (int q = 0; q < 5; ++q) acc[q] = (f32x4){bq[q], bq[q], bq[q], bq[q]};
      #pragma unroll
      for (int kk = 0; kk < 8; ++kk) {
        const int n   = mt * 16 + l15 + (kk >> 2);   // right half reads node n+1
        const int blk = (kk & 3) * 4 + quad;
        const f16x8 av = *(const f16x8*)&hS[n * 128 + ((blk ^ (n & 15)) << 3)];
        #pragma unroll
        for (int q = 0; q < 3; ++q)
          acc[q] = __builtin_amdgcn_mfma_f32_16x16x32_f16(av, Breg[kk * 3 + q], acc[q], 0, 0, 0);
        const f16x8 b3 = (kk < 4) ? Breg[24 + kk] : Blds[(kk - 4) * 512 + tid];
        acc[3] = __builtin_amdgcn_mfma_f32_16x16x32_f16(av, b3, acc[3], 0, 0, 0);
        const f16x8 b4 = Blds[(4 + kk) * 512 + tid];
        acc[4] = __builtin_amdgcn_mfma_f32_16x16x32_f16(av, b4, acc[4], 0, 0, 0);
      }
      const int n0q = mt * 16 + quad * 4;
      float c5[5];
      #pragma unroll
      for (int r = 0; r < 5; ++r) c5[r] = cS[(n0q + r) * 132 + d];
      #pragma unroll
      for (int r = 0; r < 4; ++r) {
        const float c = sig_(acc[1][r]) * c5[r] + sig_(acc[2][r]) * c5[r + 1]
                      + sig_(acc[0][r]) * tanh_(acc[3][r]);
        const float h = sig_(acc[4][r]) * tanh_(c);
        ccF[mt][r] = c; chF[mt][r] = h;
        float v = __builtin_fmaf(h, swh, c * swc);   // logit partial
        v = dpp_add<0xB1, 0xF>(v);
        v = dpp_add<0x4E, 0xF>(v);
        v = dpp_add<0x124, 0xF>(v);
        v = dpp_add<0x128, 0xF>(v);
        if (l15 == 0) {
          const int n = n0q + r;
          if (n < W) lgp[(wv << 6) + n] = v;
        }
      }
    }
    __syncthreads();

    // ---- phase B: softmax + prefix sums, redundantly per wave ----
    {
      float lg = -3.0e38f;
      if (lane < W) {
        float s = selbv;
        #pragma unroll
        for (int dg = 0; dg < 8; ++dg) s += lgp[(dg << 6) + lane];
        lg = s;
      }
      float m = lg;
      m = dpp_max<0xB1>(m); m = dpp_max<0x4E>(m);
      m = dpp_max<0x124>(m); m = dpp_max<0x128>(m);
      m = fmaxf(m, __shfl_xor(m, 16, 64));
      m = fmaxf(m, __shfl_xor(m, 32, 64));
      const float e = (lane < W) ? __expf(lg - m) : 0.f;
      float t = e;
      t = dpp_add<0xB1, 0xF>(t); t = dpp_add<0x4E, 0xF>(t);
      t = dpp_add<0x124, 0xF>(t); t = dpp_add<0x128, 0xF>(t);
      t += __shfl_xor(t, 16, 64);
      t += __shfl_xor(t, 32, 64);
      const float p = e / t;
      float cs = p;                       // inclusive scan (DPP)
      cs = dpp_add<0x111, 0xF>(cs);
      cs = dpp_add<0x112, 0xF>(cs);
      cs = dpp_add<0x114, 0xF>(cs);
      cs = dpp_add<0x118, 0xF>(cs);
      cs = dpp_add<0x142, 0xA>(cs);
      cs = dpp_add<0x143, 0xC>(cs);
      const float T = __shfl(cs, 63, 64);
      if (lane < W) {
        pS[lane]  = p;
        clS[lane] = T - cs;
        crS[lane] = cs - p;
      }
    }
    // (no barrier: each wave wrote its own redundant copy)

    // ---- phase C: blend; read-all-then-write-all per mt ----
    #pragma unroll
    for (int mt = 0; mt < 4; ++mt) if (mt < NMT) {
      const int n0q = mt * 16 + quad * 4;
      const f32x4 pv  = *(const f32x4*)&pS[n0q];
      const f32x4 clv = *(const f32x4*)&clS[n0q];
      const f32x4 crv = *(const f32x4*)&crS[n0q];
      float oh[5], c5[5];
      #pragma unroll
      for (int r = 0; r < 5; ++r) {
        oh[r] = (float)hS[hOff(n0q + r, d)];
        c5[r] = cS[(n0q + r) * 132 + d];
      }
      #pragma unroll
      for (int r = 0; r < 4; ++r) {
        const int n = n0q + r;
        if (n < W) {
          const float nh = clv[r] * oh[r] + crv[r] * oh[r + 1] + pv[r] * chF[mt][r];
          const float nc = clv[r] * c5[r] + crv[r] * c5[r + 1] + pv[r] * ccF[mt][r];
          hS[hOff(n, d)] = (f16)nh;
          cS[n * 132 + d] = nc;
        }
      }
    }
    __syncthreads();
  }

  // ---- write final state[0] TRANSPOSED: finT[k][b] ----
  if (tid < 128) {
    finT[tid * 64 + b]         = (float)hS[tid];   // hOff(0,f)=f
    finT[(128 + tid) * 64 + b] = cS[tid];          // cS row 0
  }
}

// ---- MLP head (fp32) ----
// z0: grid 64 x 512 thr; wave = 2 cols, lane = row. Direct coalesced finT
// reads (64 KB, L1/L2 resident) — no LDS staging.
__global__ __launch_bounds__(512) void z0_kernel(
    const float* __restrict__ finT, const float* __restrict__ w0,
    const float* __restrict__ b0, float* __restrict__ z0T)
{
  const int t    = threadIdx.x;
  const int lane = t & 63;         // row
  const int wvq  = t >> 6;         // 8 waves
  const int c0   = blockIdx.x * 16 + wvq * 2;
  float a0 = 0.f, a1 = 0.f;
  #pragma unroll 8
  for (int k = 0; k < 256; ++k) {
    const float x  = finT[k * 64 + lane];            // coalesced
    const float2 w = *(const float2*)&w0[k * 1024 + c0];  // wave-uniform
    a0 = __builtin_fmaf(x, w.x, a0);
    a1 = __builtin_fmaf(x, w.y, a1);
  }
  z0T[c0 * 64 + lane]       = fmaxf(a0 + b0[c0], 0.f);
  z0T[(c0 + 1) * 64 + lane] = fmaxf(a1 + b0[c0 + 1], 0.f);
}

// z1 + classifier fused: grid 256 x 256 thr; wave = 1 col, lane = row.
// Each block reduces its 4 cols' classifier contribution in LDS, then one
// atomicAdd per (row,cls). out pre-initialized to cbias by prep_kernel.
__global__ __launch_bounds__(256) void z1_kernel(
    const float* __restrict__ z0T, const float* __restrict__ w1,
    const float* __restrict__ b1, const float* __restrict__ cwt,
    float* __restrict__ out)
{
  __shared__ float P[4][64][3];
  const int t    = threadIdx.x;
  const int lane = t & 63;         // row
  const int wvq  = t >> 6;         // 4 waves
  const int col  = blockIdx.x * 4 + wvq;
  float a = 0.f;
  #pragma unroll 8
  for (int k = 0; k < 1024; ++k)
    a = __builtin_fmaf(z0T[k * 64 + lane], w1[k * 1024 + col], a);  // coalesced / uniform
  const float z = fmaxf(a + b1[col], 0.f);
  #pragma unroll
  for (int cls = 0; cls < 3; ++cls)
    P[wvq][lane][cls] = z * cwt[col * 3 + cls];
  __syncthreads();
  if (t < 192) {
    const int row = t / 3, cls = t - row * 3;
    const float s = P[0][row][cls] + P[1][row][cls] + P[2][row][cls] + P[3][row][cls];
    atomicAdd(&out[row * 3 + cls], s);
  }
}

extern "C" void kernel_launch(void* const* d_in, const int* in_sizes, int n_in,
                              void* d_out, int out_size, void* d_ws, size_t ws_size,
                              hipStream_t stream) {
  (void)in_sizes; (void)n_in; (void)out_size; (void)ws_size;
  f16*   wsB  = (f16*)d_ws;                              // 409600 B
  float* finT = (float*)((char*)d_ws + 409600);          // 65536 B
  float* z0T  = (float*)((char*)d_ws + 475136);          // 262144 B

  // allow >64 KB dynamic LDS (160 KiB/CU on gfx950); host-state call, not enqueued
  (void)hipFuncSetAttribute((const void*)pyramid_kernel,
                            hipFuncAttributeMaxDynamicSharedMemorySize, DYN_LDS);

  prep_kernel<<<dim3(80), dim3(256), 0, stream>>>(
      (const float*)d_in[3], wsB, (const float*)d_in[12], (float*)d_out);
  pyramid_kernel<<<dim3(64), dim3(512), DYN_LDS, stream>>>(
      (const int*)d_in[0], (const float*)d_in[2], wsB,
      (const float*)d_in[4], (const float*)d_in[5], (const float*)d_in[6], finT);
  z0_kernel<<<dim3(64), dim3(512), 0, stream>>>(
      finT, (const float*)d_in[7], (const float*)d_in[8], z0T);
  z1_kernel<<<dim3(256), dim3(256), 0, stream>>>(
      z0T, (const float*)d_in[9], (const float*)d_in[10],
      (const float*)d_in[11], (float*)d_out);
}

// Round 12
// 632.887 us; speedup vs baseline: 1.1586x; 1.1586x over previous
//
#include <hip/hip_runtime.h>

#define SEQ 64

typedef _Float16 f16;
typedef _Float16 f16x8 __attribute__((ext_vector_type(8)));
typedef float f32x4 __attribute__((ext_vector_type(4)));

__device__ __forceinline__ float sig_(float x) { return 1.0f / (1.0f + __expf(-x)); }
__device__ __forceinline__ float tanh_(float x) { return 1.0f - 2.0f / (1.0f + __expf(2.0f * x)); }

template<int CTRL, int RMASK>
__device__ __forceinline__ float dpp_add(float x) {
  const int t = __builtin_amdgcn_update_dpp(0, __float_as_int(x), CTRL, RMASK, 0xF, true);
  return x + __int_as_float(t);
}
template<int CTRL>
__device__ __forceinline__ float dpp_max(float x) {
  const int t = __builtin_amdgcn_update_dpp(0, __float_as_int(x), CTRL, 0xF, 0xF, true);
  return fmaxf(x, __int_as_float(t));
}

// h state: node-major, 128 f16/row, XOR-swizzled in 8-f16 (16B) blocks
__device__ __forceinline__ int hOff(int n, int f) {
  return n * 128 + ((((f >> 3) ^ (n & 15)) << 3) | (f & 7));
}

// gather one MFMA B-fragment set (kk, q) for this thread, straight from comp_W
__device__ __forceinline__ f16x8 gatherB(const float* __restrict__ cW,
                                         int kk, int q, int wv, int quad, int l15) {
  const int col = (q * 8 + wv) * 16 + l15;
  const int kb  = kk * 32 + quad * 8;
  f16x8 v;
  #pragma unroll
  for (int j = 0; j < 8; ++j) v[j] = (f16)cW[(kb + j) * 640 + col];
  return v;
}

// Dynamic-LDS partition (148.5 KiB total; 1 block/CU, 160 KiB available)
#define BLDS_OFF 0              // 12 B-frag sets: 12*512*16 = 98304
#define CS_OFF   98304          // c state f32: 65*132*4 = 34320
#define HS_OFF   132624         // h state f16 swizzled: 65*128*2 = 16640
#define LGP_OFF  149264         // logit partials: 8*64*4 = 2048
#define PS_OFF   151312         // p: 64*4
#define CLS_OFF  151568         // copy_left: 64*4
#define CRS_OFF  151824         // copy_right: 64*4
#define DYN_LDS  152080

// ---- pyramid (+ fused z0): 512 threads, 64 blocks (1 per CU) ----
// R10-proven layer loop (472 us, ~35-reg spill accepted: every pin/diet/
// launch-bounds attempt in R3-R11 regressed). New: self-gathered B (no prep
// launch) and fused z0 tail (no finT round-trip, no z0 launch).
__global__ __launch_bounds__(512, 1) void pyramid_kernel(
    const int*   __restrict__ sentences,
    const float* __restrict__ emb,
    const float* __restrict__ cW,
    const float* __restrict__ cb, const float* __restrict__ selw, const float* __restrict__ selb,
    const float* __restrict__ w0, const float* __restrict__ b0,
    const float* __restrict__ cbias,
    float* __restrict__ z0T, float* __restrict__ out)
{
  extern __shared__ __align__(16) char dyn[];
  f16x8* Blds = (f16x8*)(dyn + BLDS_OFF);
  float* cS   = (float*)(dyn + CS_OFF);
  f16*   hS   = (f16*)  (dyn + HS_OFF);
  float* lgp  = (float*)(dyn + LGP_OFF);
  float* pS   = (float*)(dyn + PS_OFF);
  float* clS  = (float*)(dyn + CLS_OFF);
  float* crS  = (float*)(dyn + CRS_OFF);

  const int tid  = threadIdx.x;
  const int b    = blockIdx.x;
  const int wv   = tid >> 6;
  const int lane = tid & 63;
  const int quad = lane >> 4;
  const int l15  = lane & 15;
  const int d    = wv * 16 + l15;

  // init logits with cbias (z1 kernel atomically accumulates onto this)
  if (b == 0 && tid < 192) out[tid] = cbias[tid % 3];

  // ---- B in LDS: s<4 -> (kk=4+s, q=3); s>=4 -> (kk=s-4, q=4) ----
  #pragma unroll
  for (int s = 0; s < 12; ++s) {
    const int kk = (s < 4) ? (4 + s) : (s - 4);
    const int q  = (s < 4) ? 3 : 4;
    Blds[s * 512 + tid] = gatherB(cW, kk, q, wv, quad, l15);
  }
  // ---- persistent B in regs: q=0..2 all kk (24) + q=3,kk=0..3 (4) = 28 sets ----
  f16x8 Breg[28];
  #pragma unroll
  for (int kk = 0; kk < 8; ++kk)
    #pragma unroll
    for (int q = 0; q < 3; ++q)
      Breg[kk * 3 + q] = gatherB(cW, kk, q, wv, quad, l15);
  #pragma unroll
  for (int kk = 0; kk < 4; ++kk)
    Breg[24 + kk] = gatherB(cW, kk, 3, wv, quad, l15);

  // ---- embedding gather: h -> LDS f16, c -> LDS f32 ----
  {
    const int s = tid >> 3, part = tid & 7;
    const int row = sentences[b * SEQ + s];
    const float4* er = (const float4*)(emb + (size_t)row * 256 + part * 32);
    #pragma unroll
    for (int i4 = 0; i4 < 8; ++i4) {
      const float4 v = er[i4];
      const float vv[4] = {v.x, v.y, v.z, v.w};
      #pragma unroll
      for (int c = 0; c < 4; ++c) {
        const int f = part * 32 + i4 * 4 + c;
        if (f < 128) hS[hOff(s, f)] = (f16)vv[c];
        else         cS[s * 132 + (f - 128)] = vv[c];
      }
    }
  }
  if (tid < 128) hS[64 * 128 + tid] = (f16)0.f;   // guard row (node 64)
  if (tid < 132) cS[64 * 132 + tid] = 0.f;
  __syncthreads();

  float bq[5];
  #pragma unroll
  for (int q = 0; q < 5; ++q) bq[q] = cb[q * 128 + d];
  const float swh = selw[d], swc = selw[128 + d], selbv = selb[0];

  // ---- pyramid: 63 sequential layers; zero global memory in the loop ----
  for (int W = 63; W >= 1; --W) {
    const int NMT = (W + 15) >> 4;
    float chF[4][4], ccF[4][4];

    // ---- phase A: MFMA + gate epilogue, one mt at a time ----
    #pragma unroll
    for (int mt = 0; mt < 4; ++mt) if (mt < NMT) {
      f32x4 acc[5];
      #pragma unroll
      for (int q = 0; q < 5; ++q) acc[q] = (f32x4){bq[q], bq[q], bq[q], bq[q]};
      #pragma unroll
      for (int kk = 0; kk < 8; ++kk) {
        const int n   = mt * 16 + l15 + (kk >> 2);   // right half reads node n+1
        const int blk = (kk & 3) * 4 + quad;
        const f16x8 av = *(const f16x8*)&hS[n * 128 + ((blk ^ (n & 15)) << 3)];
        #pragma unroll
        for (int q = 0; q < 3; ++q)
          acc[q] = __builtin_amdgcn_mfma_f32_16x16x32_f16(av, Breg[kk * 3 + q], acc[q], 0, 0, 0);
        const f16x8 b3 = (kk < 4) ? Breg[24 + kk] : Blds[(kk - 4) * 512 + tid];
        acc[3] = __builtin_amdgcn_mfma_f32_16x16x32_f16(av, b3, acc[3], 0, 0, 0);
        const f16x8 b4 = Blds[(4 + kk) * 512 + tid];
        acc[4] = __builtin_amdgcn_mfma_f32_16x16x32_f16(av, b4, acc[4], 0, 0, 0);
      }
      const int n0q = mt * 16 + quad * 4;
      float c5[5];
      #pragma unroll
      for (int r = 0; r < 5; ++r) c5[r] = cS[(n0q + r) * 132 + d];
      #pragma unroll
      for (int r = 0; r < 4; ++r) {
        const float c = sig_(acc[1][r]) * c5[r] + sig_(acc[2][r]) * c5[r + 1]
                      + sig_(acc[0][r]) * tanh_(acc[3][r]);
        const float h = sig_(acc[4][r]) * tanh_(c);
        ccF[mt][r] = c; chF[mt][r] = h;
        float v = __builtin_fmaf(h, swh, c * swc);   // logit partial
        v = dpp_add<0xB1, 0xF>(v);
        v = dpp_add<0x4E, 0xF>(v);
        v = dpp_add<0x124, 0xF>(v);
        v = dpp_add<0x128, 0xF>(v);
        if (l15 == 0) {
          const int n = n0q + r;
          if (n < W) lgp[(wv << 6) + n] = v;
        }
      }
    }
    __syncthreads();

    // ---- phase B: softmax + prefix sums, redundantly per wave ----
    {
      float lg = -3.0e38f;
      if (lane < W) {
        float s = selbv;
        #pragma unroll
        for (int dg = 0; dg < 8; ++dg) s += lgp[(dg << 6) + lane];
        lg = s;
      }
      float m = lg;
      m = dpp_max<0xB1>(m); m = dpp_max<0x4E>(m);
      m = dpp_max<0x124>(m); m = dpp_max<0x128>(m);
      m = fmaxf(m, __shfl_xor(m, 16, 64));
      m = fmaxf(m, __shfl_xor(m, 32, 64));
      const float e = (lane < W) ? __expf(lg - m) : 0.f;
      float t = e;
      t = dpp_add<0xB1, 0xF>(t); t = dpp_add<0x4E, 0xF>(t);
      t = dpp_add<0x124, 0xF>(t); t = dpp_add<0x128, 0xF>(t);
      t += __shfl_xor(t, 16, 64);
      t += __shfl_xor(t, 32, 64);
      const float p = e / t;
      float cs = p;                       // inclusive scan (DPP)
      cs = dpp_add<0x111, 0xF>(cs);
      cs = dpp_add<0x112, 0xF>(cs);
      cs = dpp_add<0x114, 0xF>(cs);
      cs = dpp_add<0x118, 0xF>(cs);
      cs = dpp_add<0x142, 0xA>(cs);
      cs = dpp_add<0x143, 0xC>(cs);
      const float T = __shfl(cs, 63, 64);
      if (lane < W) {
        pS[lane]  = p;
        clS[lane] = T - cs;
        crS[lane] = cs - p;
      }
    }
    // (no barrier: each wave wrote its own redundant copy)

    // ---- phase C: blend; read-all-then-write-all per mt ----
    #pragma unroll
    for (int mt = 0; mt < 4; ++mt) if (mt < NMT) {
      const int n0q = mt * 16 + quad * 4;
      const f32x4 pv  = *(const f32x4*)&pS[n0q];
      const f32x4 clv = *(const f32x4*)&clS[n0q];
      const f32x4 crv = *(const f32x4*)&crS[n0q];
      float oh[5], c5[5];
      #pragma unroll
      for (int r = 0; r < 5; ++r) {
        oh[r] = (float)hS[hOff(n0q + r, d)];
        c5[r] = cS[(n0q + r) * 132 + d];
      }
      #pragma unroll
      for (int r = 0; r < 4; ++r) {
        const int n = n0q + r;
        if (n < W) {
          const float nh = clv[r] * oh[r] + crv[r] * oh[r + 1] + pv[r] * chF[mt][r];
          const float nc = clv[r] * c5[r] + crv[r] * c5[r + 1] + pv[r] * ccF[mt][r];
          hS[hOff(n, d)] = (f16)nh;
          cS[n * 132 + d] = nc;
        }
      }
    }
    __syncthreads();
  }

  // ---- fused z0: x = [h0||c0] (in LDS), each thread 2 cols of mlp_w0 ----
  {
    const int c0 = 2 * tid;
    float a0 = 0.f, a1 = 0.f;
    #pragma unroll 8
    for (int k = 0; k < 128; ++k) {
      const float x  = (float)hS[k];                       // LDS broadcast
      const float2 w = *(const float2*)&w0[k * 1024 + c0]; // coalesced
      a0 = __builtin_fmaf(x, w.x, a0);
      a1 = __builtin_fmaf(x, w.y, a1);
    }
    #pragma unroll 8
    for (int k = 0; k < 128; ++k) {
      const float x  = cS[k];                              // LDS broadcast
      const float2 w = *(const float2*)&w0[(128 + k) * 1024 + c0];
      a0 = __builtin_fmaf(x, w.x, a0);
      a1 = __builtin_fmaf(x, w.y, a1);
    }
    z0T[c0 * 64 + b]       = fmaxf(a0 + b0[c0], 0.f);      // transposed for z1
    z0T[(c0 + 1) * 64 + b] = fmaxf(a1 + b0[c0 + 1], 0.f);
  }
}

// ---- z1 + classifier fused: grid 256 x 256 thr; wave = 1 col, lane = row ----
// w1 read once globally (16 KB/CU); block-reduces classifier partials, one
// atomicAdd per (row,cls). out pre-initialized to cbias by pyramid block 0.
__global__ __launch_bounds__(256) void z1_kernel(
    const float* __restrict__ z0T, const float* __restrict__ w1,
    const float* __restrict__ b1, const float* __restrict__ cwt,
    float* __restrict__ out)
{
  __shared__ float P[4][64][3];
  const int t    = threadIdx.x;
  const int lane = t & 63;         // row
  const int wvq  = t >> 6;         // 4 waves
  const int col  = blockIdx.x * 4 + wvq;
  float a = 0.f;
  #pragma unroll 8
  for (int k = 0; k < 1024; ++k)
    a = __builtin_fmaf(z0T[k * 64 + lane], w1[k * 1024 + col], a);  // coalesced / uniform
  const float z = fmaxf(a + b1[col], 0.f);
  #pragma unroll
  for (int cls = 0; cls < 3; ++cls)
    P[wvq][lane][cls] = z * cwt[col * 3 + cls];
  __syncthreads();
  if (t < 192) {
    const int row = t / 3, cls = t - row * 3;
    const float s = P[0][row][cls] + P[1][row][cls] + P[2][row][cls] + P[3][row][cls];
    atomicAdd(&out[row * 3 + cls], s);
  }
}

extern "C" void kernel_launch(void* const* d_in, const int* in_sizes, int n_in,
                              void* d_out, int out_size, void* d_ws, size_t ws_size,
                              hipStream_t stream) {
  (void)in_sizes; (void)n_in; (void)out_size; (void)ws_size;
  float* z0T = (float*)d_ws;                             // 262144 B

  // allow >64 KB dynamic LDS (160 KiB/CU on gfx950); host-state call, not enqueued
  (void)hipFuncSetAttribute((const void*)pyramid_kernel,
                            hipFuncAttributeMaxDynamicSharedMemorySize, DYN_LDS);

  pyramid_kernel<<<dim3(64), dim3(512), DYN_LDS, stream>>>(
      (const int*)d_in[0],          // sentences
      (const float*)d_in[2],        // emb
      (const float*)d_in[3],        // comp_W (self-gathered to fragments)
      (const float*)d_in[4],        // comp_b
      (const float*)d_in[5],        // sel_w
      (const float*)d_in[6],        // sel_b
      (const float*)d_in[7],        // mlp_w0
      (const float*)d_in[8],        // mlp_b0
      (const float*)d_in[12],       // cls_b (out init)
      z0T, (float*)d_out);
  z1_kernel<<<dim3(256), dim3(256), 0, stream>>>(
      z0T,
      (const float*)d_in[9],        // mlp_w1
      (const float*)d_in[10],       // mlp_b1
      (const float*)d_in[11],       // cls_w
      (float*)d_out);
}

// Round 13
// 598.615 us; speedup vs baseline: 1.2249x; 1.0573x over previous
//
#include <hip/hip_runtime.h>

#define SEQ 64

typedef _Float16 f16;
typedef _Float16 f16x8 __attribute__((ext_vector_type(8)));
typedef _Float16 f16x2 __attribute__((ext_vector_type(2)));
typedef float f32x4 __attribute__((ext_vector_type(4)));

__device__ __forceinline__ float sig_(float x) { return 1.0f / (1.0f + __expf(-x)); }
__device__ __forceinline__ float tanh_(float x) { return 1.0f - 2.0f / (1.0f + __expf(2.0f * x)); }

template<int CTRL, int RMASK>
__device__ __forceinline__ float dpp_add(float x) {
  const int t = __builtin_amdgcn_update_dpp(0, __float_as_int(x), CTRL, RMASK, 0xF, true);
  return x + __int_as_float(t);
}
template<int CTRL>
__device__ __forceinline__ float dpp_max(float x) {
  const int t = __builtin_amdgcn_update_dpp(0, __float_as_int(x), CTRL, 0xF, 0xF, true);
  return fmaxf(x, __int_as_float(t));
}
__device__ __forceinline__ float red16(float v) {   // sum over 16-lane row
  v = dpp_add<0xB1, 0xF>(v);
  v = dpp_add<0x4E, 0xF>(v);
  v = dpp_add<0x124, 0xF>(v);
  v = dpp_add<0x128, 0xF>(v);
  return v;
}

// h state: node-major, 128 f16/row, XOR-swizzled in 8-f16 (16B) blocks
__device__ __forceinline__ int hOff(int n, int f) {
  return n * 128 + ((((f >> 3) ^ (n & 15)) << 3) | (f & 7));
}

// gather one MFMA B-fragment set (kk, q) for this thread, straight from comp_W
__device__ __forceinline__ f16x8 gatherB(const float* __restrict__ cW,
                                         int kk, int q, int wv, int quad, int l15) {
  const int col = (q * 8 + wv) * 16 + l15;
  const int kb  = kk * 32 + quad * 8;
  f16x8 v;
  #pragma unroll
  for (int j = 0; j < 8; ++j) v[j] = (f16)cW[(kb + j) * 640 + col];
  return v;
}

// Dynamic-LDS partition (148.5 KiB total; 1 block/CU, 160 KiB available)
#define BLDS_OFF 0              // 12 B-frag sets: 12*512*16 = 98304
#define CS_OFF   98304          // c state f32: 65*132*4 = 34320
#define HS_OFF   132624         // h state f16 swizzled: 65*128*2 = 16640
#define LGP_OFF  149264         // logit partials: 8*64*4 = 2048
#define PS_OFF   151312         // p: 64*4
#define CLS_OFF  151568         // copy_left: 64*4
#define CRS_OFF  151824         // copy_right: 64*4
#define DYN_LDS  152080

// ---- pyramid (+ fused z0): 512 threads, 64 blocks (1 per CU) ----
// R12-proven layer loop (494 us). Only change: z0 output is f16 [row][k].
__global__ __launch_bounds__(512, 1) void pyramid_kernel(
    const int*   __restrict__ sentences,
    const float* __restrict__ emb,
    const float* __restrict__ cW,
    const float* __restrict__ cb, const float* __restrict__ selw, const float* __restrict__ selb,
    const float* __restrict__ w0, const float* __restrict__ b0,
    const float* __restrict__ cbias,
    f16* __restrict__ z0h, float* __restrict__ out)
{
  extern __shared__ __align__(16) char dyn[];
  f16x8* Blds = (f16x8*)(dyn + BLDS_OFF);
  float* cS   = (float*)(dyn + CS_OFF);
  f16*   hS   = (f16*)  (dyn + HS_OFF);
  float* lgp  = (float*)(dyn + LGP_OFF);
  float* pS   = (float*)(dyn + PS_OFF);
  float* clS  = (float*)(dyn + CLS_OFF);
  float* crS  = (float*)(dyn + CRS_OFF);

  const int tid  = threadIdx.x;
  const int b    = blockIdx.x;
  const int wv   = tid >> 6;
  const int lane = tid & 63;
  const int quad = lane >> 4;
  const int l15  = lane & 15;
  const int d    = wv * 16 + l15;

  // init logits with cbias (z1 kernel atomically accumulates onto this)
  if (b == 0 && tid < 192) out[tid] = cbias[tid % 3];

  // ---- B in LDS: s<4 -> (kk=4+s, q=3); s>=4 -> (kk=s-4, q=4) ----
  #pragma unroll
  for (int s = 0; s < 12; ++s) {
    const int kk = (s < 4) ? (4 + s) : (s - 4);
    const int q  = (s < 4) ? 3 : 4;
    Blds[s * 512 + tid] = gatherB(cW, kk, q, wv, quad, l15);
  }
  // ---- persistent B in regs: q=0..2 all kk (24) + q=3,kk=0..3 (4) = 28 sets ----
  f16x8 Breg[28];
  #pragma unroll
  for (int kk = 0; kk < 8; ++kk)
    #pragma unroll
    for (int q = 0; q < 3; ++q)
      Breg[kk * 3 + q] = gatherB(cW, kk, q, wv, quad, l15);
  #pragma unroll
  for (int kk = 0; kk < 4; ++kk)
    Breg[24 + kk] = gatherB(cW, kk, 3, wv, quad, l15);

  // ---- embedding gather: h -> LDS f16, c -> LDS f32 ----
  {
    const int s = tid >> 3, part = tid & 7;
    const int row = sentences[b * SEQ + s];
    const float4* er = (const float4*)(emb + (size_t)row * 256 + part * 32);
    #pragma unroll
    for (int i4 = 0; i4 < 8; ++i4) {
      const float4 v = er[i4];
      const float vv[4] = {v.x, v.y, v.z, v.w};
      #pragma unroll
      for (int c = 0; c < 4; ++c) {
        const int f = part * 32 + i4 * 4 + c;
        if (f < 128) hS[hOff(s, f)] = (f16)vv[c];
        else         cS[s * 132 + (f - 128)] = vv[c];
      }
    }
  }
  if (tid < 128) hS[64 * 128 + tid] = (f16)0.f;   // guard row (node 64)
  if (tid < 132) cS[64 * 132 + tid] = 0.f;
  __syncthreads();

  float bq[5];
  #pragma unroll
  for (int q = 0; q < 5; ++q) bq[q] = cb[q * 128 + d];
  const float swh = selw[d], swc = selw[128 + d], selbv = selb[0];

  // ---- pyramid: 63 sequential layers; zero global memory in the loop ----
  for (int W = 63; W >= 1; --W) {
    const int NMT = (W + 15) >> 4;
    float chF[4][4], ccF[4][4];

    // ---- phase A: MFMA + gate epilogue, one mt at a time ----
    #pragma unroll
    for (int mt = 0; mt < 4; ++mt) if (mt < NMT) {
      f32x4 acc[5];
      #pragma unroll
      for (int q = 0; q < 5; ++q) acc[q] = (f32x4){bq[q], bq[q], bq[q], bq[q]};
      #pragma unroll
      for (int kk = 0; kk < 8; ++kk) {
        const int n   = mt * 16 + l15 + (kk >> 2);   // right half reads node n+1
        const int blk = (kk & 3) * 4 + quad;
        const f16x8 av = *(const f16x8*)&hS[n * 128 + ((blk ^ (n & 15)) << 3)];
        #pragma unroll
        for (int q = 0; q < 3; ++q)
          acc[q] = __builtin_amdgcn_mfma_f32_16x16x32_f16(av, Breg[kk * 3 + q], acc[q], 0, 0, 0);
        const f16x8 b3 = (kk < 4) ? Breg[24 + kk] : Blds[(kk - 4) * 512 + tid];
        acc[3] = __builtin_amdgcn_mfma_f32_16x16x32_f16(av, b3, acc[3], 0, 0, 0);
        const f16x8 b4 = Blds[(4 + kk) * 512 + tid];
        acc[4] = __builtin_amdgcn_mfma_f32_16x16x32_f16(av, b4, acc[4], 0, 0, 0);
      }
      const int n0q = mt * 16 + quad * 4;
      float c5[5];
      #pragma unroll
      for (int r = 0; r < 5; ++r) c5[r] = cS[(n0q + r) * 132 + d];
      #pragma unroll
      for (int r = 0; r < 4; ++r) {
        const float c = sig_(acc[1][r]) * c5[r] + sig_(acc[2][r]) * c5[r + 1]
                      + sig_(acc[0][r]) * tanh_(acc[3][r]);
        const float h = sig_(acc[4][r]) * tanh_(c);
        ccF[mt][r] = c; chF[mt][r] = h;
        float v = red16(__builtin_fmaf(h, swh, c * swc));   // logit partial
        if (l15 == 0) {
          const int n = n0q + r;
          if (n < W) lgp[(wv << 6) + n] = v;
        }
      }
    }
    __syncthreads();

    // ---- phase B: softmax + prefix sums, redundantly per wave ----
    {
      float lg = -3.0e38f;
      if (lane < W) {
        float s = selbv;
        #pragma unroll
        for (int dg = 0; dg < 8; ++dg) s += lgp[(dg << 6) + lane];
        lg = s;
      }
      float m = lg;
      m = dpp_max<0xB1>(m); m = dpp_max<0x4E>(m);
      m = dpp_max<0x124>(m); m = dpp_max<0x128>(m);
      m = fmaxf(m, __shfl_xor(m, 16, 64));
      m = fmaxf(m, __shfl_xor(m, 32, 64));
      const float e = (lane < W) ? __expf(lg - m) : 0.f;
      float t = e;
      t = dpp_add<0xB1, 0xF>(t); t = dpp_add<0x4E, 0xF>(t);
      t = dpp_add<0x124, 0xF>(t); t = dpp_add<0x128, 0xF>(t);
      t += __shfl_xor(t, 16, 64);
      t += __shfl_xor(t, 32, 64);
      const float p = e / t;
      float cs = p;                       // inclusive scan (DPP)
      cs = dpp_add<0x111, 0xF>(cs);
      cs = dpp_add<0x112, 0xF>(cs);
      cs = dpp_add<0x114, 0xF>(cs);
      cs = dpp_add<0x118, 0xF>(cs);
      cs = dpp_add<0x142, 0xA>(cs);
      cs = dpp_add<0x143, 0xC>(cs);
      const float T = __shfl(cs, 63, 64);
      if (lane < W) {
        pS[lane]  = p;
        clS[lane] = T - cs;
        crS[lane] = cs - p;
      }
    }
    // (no barrier: each wave wrote its own redundant copy)

    // ---- phase C: blend; read-all-then-write-all per mt ----
    #pragma unroll
    for (int mt = 0; mt < 4; ++mt) if (mt < NMT) {
      const int n0q = mt * 16 + quad * 4;
      const f32x4 pv  = *(const f32x4*)&pS[n0q];
      const f32x4 clv = *(const f32x4*)&clS[n0q];
      const f32x4 crv = *(const f32x4*)&crS[n0q];
      float oh[5], c5[5];
      #pragma unroll
      for (int r = 0; r < 5; ++r) {
        oh[r] = (float)hS[hOff(n0q + r, d)];
        c5[r] = cS[(n0q + r) * 132 + d];
      }
      #pragma unroll
      for (int r = 0; r < 4; ++r) {
        const int n = n0q + r;
        if (n < W) {
          const float nh = clv[r] * oh[r] + crv[r] * oh[r + 1] + pv[r] * chF[mt][r];
          const float nc = clv[r] * c5[r] + crv[r] * c5[r + 1] + pv[r] * ccF[mt][r];
          hS[hOff(n, d)] = (f16)nh;
          cS[n * 132 + d] = nc;
        }
      }
    }
    __syncthreads();
  }

  // ---- fused z0: x = [h0||c0] (in LDS); each thread 2 cols; output f16 ----
  {
    const int c0 = 2 * tid;
    float a0 = 0.f, a1 = 0.f;
    #pragma unroll 8
    for (int k = 0; k < 128; ++k) {
      const float x  = (float)hS[k];                       // LDS broadcast
      const float2 w = *(const float2*)&w0[k * 1024 + c0]; // coalesced
      a0 = __builtin_fmaf(x, w.x, a0);
      a1 = __builtin_fmaf(x, w.y, a1);
    }
    #pragma unroll 8
    for (int k = 0; k < 128; ++k) {
      const float x  = cS[k];                              // LDS broadcast
      const float2 w = *(const float2*)&w0[(128 + k) * 1024 + c0];
      a0 = __builtin_fmaf(x, w.x, a0);
      a1 = __builtin_fmaf(x, w.y, a1);
    }
    f16x2 p;
    p[0] = (f16)fmaxf(a0 + b0[c0], 0.f);
    p[1] = (f16)fmaxf(a1 + b0[c0 + 1], 0.f);
    *(f16x2*)&z0h[b * 1024 + c0] = p;      // z0h[row=b][k], A-operand layout
  }
}

// ---- z1 + classifier, MFMA: 64 blocks x 256 thr (4 waves) ----
// Block = 16 cols of w1; M=64 rows x K=1024 in 4 chunks of 256.
// Wave wv owns M-tile rows [wv*16, wv*16+16). f32 accumulation; classifier
// partials DPP-reduced over the 16 col-lanes, atomicAdd onto cbias-init out.
#define ZROW 264   // 256 + 8 f16 pad (4-bank row stride)
__global__ __launch_bounds__(256) void z1_kernel(
    const f16* __restrict__ z0h, const float* __restrict__ w1,
    const float* __restrict__ b1, const float* __restrict__ cwt,
    float* __restrict__ out)
{
  __shared__ __align__(16) f16 ZL[64 * ZROW];   // 33792 B
  __shared__ __align__(16) f16 WL[16 * ZROW];   // 8448 B
  const int t    = threadIdx.x;
  const int wv   = t >> 6;
  const int lane = t & 63;
  const int quad = lane >> 4;
  const int l15  = lane & 15;
  const int c0   = blockIdx.x * 16;

  f32x4 acc = (f32x4){0.f, 0.f, 0.f, 0.f};
  for (int k0 = 0; k0 < 1024; k0 += 256) {
    __syncthreads();                      // protect previous chunk's reads
    // stage z0h chunk: 64 rows x 256 k (f16), b128 copies
    #pragma unroll
    for (int i = 0; i < 8; ++i) {
      const int idx8 = (t + i * 256) * 8;          // 0..16376
      const int row  = idx8 >> 8;
      const int ko   = idx8 & 255;
      *(f16x8*)&ZL[row * ZROW + ko] = *(const f16x8*)&z0h[row * 1024 + k0 + ko];
    }
    // stage w1 slice transposed: WL[col][k] f16 (converted from f32)
    #pragma unroll
    for (int i = 0; i < 16; ++i) {
      const int idx = t + i * 256;                  // 0..4095
      const int kc = idx >> 4, ci = idx & 15;       // coalesced over ci
      WL[ci * ZROW + kc] = (f16)w1[(k0 + kc) * 1024 + c0 + ci];
    }
    __syncthreads();
    #pragma unroll
    for (int kk = 0; kk < 8; ++kk) {
      const f16x8 av = *(const f16x8*)&ZL[(wv * 16 + l15) * ZROW + kk * 32 + quad * 8];
      const f16x8 bv = *(const f16x8*)&WL[l15 * ZROW + kk * 32 + quad * 8];
      acc = __builtin_amdgcn_mfma_f32_16x16x32_f16(av, bv, acc, 0, 0, 0);
    }
  }

  // epilogue: z1 = relu(acc + b1); classifier partials over this block's 16 cols
  const int col = c0 + l15;
  const float bias = b1[col];
  const float cw0 = cwt[col * 3], cw1 = cwt[col * 3 + 1], cw2 = cwt[col * 3 + 2];
  #pragma unroll
  for (int r = 0; r < 4; ++r) {
    const int row = wv * 16 + quad * 4 + r;
    const float z = fmaxf(acc[r] + bias, 0.f);
    const float p0 = red16(z * cw0);
    const float p1 = red16(z * cw1);
    const float p2 = red16(z * cw2);
    if (l15 == 0) {
      atomicAdd(&out[row * 3 + 0], p0);
      atomicAdd(&out[row * 3 + 1], p1);
      atomicAdd(&out[row * 3 + 2], p2);
    }
  }
}

extern "C" void kernel_launch(void* const* d_in, const int* in_sizes, int n_in,
                              void* d_out, int out_size, void* d_ws, size_t ws_size,
                              hipStream_t stream) {
  (void)in_sizes; (void)n_in; (void)out_size; (void)ws_size;
  f16* z0h = (f16*)d_ws;                                 // 64*1024*2 = 131072 B

  // allow >64 KB dynamic LDS (160 KiB/CU on gfx950); host-state call, not enqueued
  (void)hipFuncSetAttribute((const void*)pyramid_kernel,
                            hipFuncAttributeMaxDynamicSharedMemorySize, DYN_LDS);

  pyramid_kernel<<<dim3(64), dim3(512), DYN_LDS, stream>>>(
      (const int*)d_in[0],          // sentences
      (const float*)d_in[2],        // emb
      (const float*)d_in[3],        // comp_W (self-gathered to fragments)
      (const float*)d_in[4],        // comp_b
      (const float*)d_in[5],        // sel_w
      (const float*)d_in[6],        // sel_b
      (const float*)d_in[7],        // mlp_w0
      (const float*)d_in[8],        // mlp_b0
      (const float*)d_in[12],       // cls_b (out init)
      z0h, (float*)d_out);
  z1_kernel<<<dim3(64), dim3(256), 0, stream>>>(
      z0h,
      (const float*)d_in[9],        // mlp_w1
      (const float*)d_in[10],       // mlp_b1
      (const float*)d_in[11],       // cls_w
      (float*)d_out);
}